// Round 4
// baseline (313.808 us; speedup 1.0000x reference)
//
#include <hip/hip_runtime.h>
#include <hip/hip_bf16.h>
#include <math.h>

#define NEG 0.2f

typedef __attribute__((ext_vector_type(4))) float f4;
typedef __attribute__((ext_vector_type(8))) short s8;

__device__ __forceinline__ short f2bf(float f) {
    unsigned u = __float_as_uint(f);
    u += 0x7fff + ((u >> 16) & 1);          // round-to-nearest-even
    return (short)(u >> 16);
}
__device__ __forceinline__ unsigned pk2(float a, float b) {
    union { __hip_bfloat162 h; unsigned u; } c;
    c.h = __float22bfloat162_rn(make_float2(a, b));   // v_cvt_pk_bf16_f32
    return c.u;
}
__device__ __forceinline__ float bf2f(unsigned short s) {
    return __uint_as_float(((unsigned)s) << 16);
}

// ---------------------------------------------------------------------------
// Kernel 0: prep — Wt[n][k] = bf16(W[k][n])  +  deg[] = 0
// ---------------------------------------------------------------------------
__global__ void prep(const float* __restrict__ W, short* __restrict__ Wt,
                     int* __restrict__ deg, int N)
{
    int id = blockIdx.x * 256 + threadIdx.x;
    if (id < 65536) {
        int n = id >> 8, k = id & 255;
        Wt[id] = f2bf(W[k * 256 + n]);
    }
    if (id < N) deg[id] = 0;
}

// ---------------------------------------------------------------------------
// Kernel 1: LDS-free MFMA GEMM, h^T layout D[ch][node].
// Block = 256 ch x 64 nodes, 4 waves, wave wv = head wv.
// A-frags: Wt rows (L2-resident, 16B/lane). B-frags: x fp32 direct loads
// (coalesced 64B/row segments) packed in-register to bf16. No syncthreads.
// ---------------------------------------------------------------------------
__global__ __launch_bounds__(256) void gemm_attn(
    const float* __restrict__ x, const short* __restrict__ Wt,
    const float* __restrict__ att_src, const float* __restrict__ att_dst,
    short* __restrict__ hb, float* __restrict__ a_src_n,
    float* __restrict__ a_dst_n, int M)
{
    const int t = threadIdx.x;
    const int lane = t & 63, wv = t >> 6;
    const int quad = lane >> 4, l15 = lane & 15;
    const int n0 = blockIdx.x * 64;
    const int hd = wv;

    const float* xp[4];
    int node[4]; bool ok[4];
#pragma unroll
    for (int j = 0; j < 4; ++j) {
        node[j] = n0 + j * 16 + l15;
        ok[j] = node[j] < M;
        int cr = ok[j] ? node[j] : (M - 1);
        xp[j] = x + (size_t)cr * 256 + quad * 8;
    }
    const short* wb = Wt + (size_t)(hd * 64 + l15) * 256 + quad * 8;

    f4 acc[4][4];   // [i: ch frag][j: node frag]
#pragma unroll
    for (int i = 0; i < 4; ++i)
#pragma unroll
        for (int j = 0; j < 4; ++j) acc[i][j] = (f4)(0.f);

#pragma unroll
    for (int ks = 0; ks < 8; ++ks) {
        s8 bf[4];
#pragma unroll
        for (int j = 0; j < 4; ++j) {
            float4 p0 = *(const float4*)(xp[j] + ks * 32);
            float4 p1 = *(const float4*)(xp[j] + ks * 32 + 4);
            union { uint4 u; s8 s; } c;
            c.u = make_uint4(pk2(p0.x, p0.y), pk2(p0.z, p0.w),
                             pk2(p1.x, p1.y), pk2(p1.z, p1.w));
            bf[j] = c.s;
        }
        s8 af[4];
#pragma unroll
        for (int i = 0; i < 4; ++i)
            af[i] = *(const s8*)(wb + (size_t)(i * 16) * 256 + ks * 32);
#pragma unroll
        for (int i = 0; i < 4; ++i)
#pragma unroll
            for (int j = 0; j < 4; ++j)
                acc[i][j] = __builtin_amdgcn_mfma_f32_16x16x32_bf16(af[i], bf[j], acc[i][j], 0, 0, 0);
    }

    // att vectors for this lane's channels: ch = hd*64 + i*16 + quad*4 + rr
    float4 asv[4], adv[4];
#pragma unroll
    for (int i = 0; i < 4; ++i) {
        asv[i] = *(const float4*)(att_src + hd * 64 + i * 16 + quad * 4);
        adv[i] = *(const float4*)(att_dst + hd * 64 + i * 16 + quad * 4);
    }

#pragma unroll
    for (int j = 0; j < 4; ++j) {
        float ps = 0.f, pd = 0.f;
#pragma unroll
        for (int i = 0; i < 4; ++i) {
            ps = fmaf(acc[i][j][0], asv[i].x, ps); pd = fmaf(acc[i][j][0], adv[i].x, pd);
            ps = fmaf(acc[i][j][1], asv[i].y, ps); pd = fmaf(acc[i][j][1], adv[i].y, pd);
            ps = fmaf(acc[i][j][2], asv[i].z, ps); pd = fmaf(acc[i][j][2], adv[i].z, pd);
            ps = fmaf(acc[i][j][3], asv[i].w, ps); pd = fmaf(acc[i][j][3], adv[i].w, pd);
        }
        ps += __shfl_xor(ps, 16); ps += __shfl_xor(ps, 32);
        pd += __shfl_xor(pd, 16); pd += __shfl_xor(pd, 32);
        if (ok[j] && quad == 0) {
            a_src_n[node[j] * 4 + hd] = ps;
            a_dst_n[node[j] * 4 + hd] = pd;
        }
        if (ok[j]) {
#pragma unroll
            for (int i = 0; i < 4; ++i) {
                uint2 pk = make_uint2(pk2(acc[i][j][0], acc[i][j][1]),
                                      pk2(acc[i][j][2], acc[i][j][3]));
                *(uint2*)&hb[(size_t)node[j] * 256 + hd * 64 + i * 16 + quad * 4] = pk;
            }
        }
    }
}

// ---------------------------------------------------------------------------
// Kernel 2: degree histogram over dst (edges + self loops)
// ---------------------------------------------------------------------------
__global__ void hist_kernel(const int* __restrict__ ei, int* __restrict__ deg,
                            int E, int N)
{
    int e = blockIdx.x * 256 + threadIdx.x;
    if (e >= E + N) return;
    int dte = (e < E) ? ei[E + e] : (e - E);
    atomicAdd(&deg[dte], 1);
}

// ---------------------------------------------------------------------------
// Kernels 3a/3b/3c: multi-block exclusive scan deg[N] -> off[N+1], cur[N]
// ---------------------------------------------------------------------------
__global__ __launch_bounds__(1024) void scan1(const int* __restrict__ deg,
                                              int* __restrict__ off,
                                              int* __restrict__ bsum, int N)
{
    __shared__ int wsum[16], wexc[16];
    const int t = threadIdx.x, lane = t & 63, w = t >> 6;
    const int idx = blockIdx.x * 1024 + t;
    int v = (idx < N) ? deg[idx] : 0;
    int val = v;
#pragma unroll
    for (int o = 1; o < 64; o <<= 1) {
        int u = __shfl_up(val, o);
        if (lane >= o) val += u;
    }
    if (lane == 63) wsum[w] = val;
    __syncthreads();
    if (t < 16) {
        int s = wsum[t];
#pragma unroll
        for (int o = 1; o < 16; o <<= 1) {
            int u = __shfl_up(s, o, 16);
            if (t >= o) s += u;
        }
        wexc[t] = s - wsum[t];
        if (t == 15) bsum[blockIdx.x] = s;
    }
    __syncthreads();
    if (idx < N) off[idx] = wexc[w] + val - v;
}

__global__ void scan2(const int* __restrict__ bsum, int* __restrict__ bexc,
                      int* __restrict__ off, int nb, int N)
{
    int t = threadIdx.x;  // 64 threads, nb <= 64
    int s = (t < nb) ? bsum[t] : 0;
    int val = s;
#pragma unroll
    for (int o = 1; o < 64; o <<= 1) {
        int u = __shfl_up(val, o);
        if (t >= o) val += u;
    }
    if (t < nb) bexc[t] = val - s;
    if (t == 63) off[N] = val;
}

__global__ __launch_bounds__(1024) void scan3(int* __restrict__ off,
                                              int* __restrict__ cur,
                                              const int* __restrict__ bexc, int N)
{
    int idx = blockIdx.x * 1024 + threadIdx.x;
    if (idx < N) {
        int o = off[idx] + bexc[blockIdx.x];
        off[idx] = o;
        cur[idx] = o;
    }
}

// ---------------------------------------------------------------------------
// Kernel 4: scatter edges into CSR by dst
// ---------------------------------------------------------------------------
__global__ void scatter_kernel(const int* __restrict__ ei, int* __restrict__ cur,
                               int* __restrict__ csr, int E, int N)
{
    int e = blockIdx.x * 256 + threadIdx.x;
    if (e >= E + N) return;
    int s, dte;
    if (e < E) { s = ei[e]; dte = ei[E + e]; }
    else       { s = e - E; dte = s; }
    int pos = atomicAdd(&cur[dte], 1);
    csr[pos] = s;
}

// ---------------------------------------------------------------------------
// Kernel 5: segment softmax + aggregation. One wave per dst.
// Producer: lane j -> un-normalized weight (4 heads) + src id into LDS.
// Consumer: two half-waves each gather a FULL 512B hb row (uint4/lane,
// 16B); lane owns 8 contiguous channels (one head); 2x unroll = 4 rows
// in flight per wave. Halves merged via shfl_xor(32) at the end.
// ---------------------------------------------------------------------------
__global__ __launch_bounds__(256) void aggregate(const short* __restrict__ hb,
                                                 const float* __restrict__ a_src_n,
                                                 const float* __restrict__ a_dst_n,
                                                 const int* __restrict__ off,
                                                 const int* __restrict__ csr,
                                                 const float* __restrict__ bias,
                                                 float* __restrict__ out, int N)
{
    __shared__ float lds_w[4][64][4];
    __shared__ int   lds_s[4][64];
    const int wv = threadIdx.x >> 6;
    const int lane = threadIdx.x & 63;
    const int half = lane >> 5, l31 = lane & 31;
    const int n = blockIdx.x * 4 + wv;
    if (n >= N) return;

    const int base = off[n];
    const int d = off[n + 1] - base;
    const float4 ad = *(const float4*)(a_dst_n + 4 * n);
    const int hl = l31 >> 3;             // head of this lane's 8 channels

    float acc[8] = {0.f, 0.f, 0.f, 0.f, 0.f, 0.f, 0.f, 0.f};
    float4 sum = make_float4(0.f, 0.f, 0.f, 0.f);
    const uint4* hp = (const uint4*)hb;

    for (int c0 = 0; c0 < d; c0 += 64) {
        int j = c0 + lane;
        int s = 0;
        float4 w4 = make_float4(0.f, 0.f, 0.f, 0.f);
        if (j < d) {
            s = csr[base + j];
            float4 as = *(const float4*)(a_src_n + 4 * s);
            float lx = as.x + ad.x; lx = lx >= 0.f ? lx : NEG * lx;
            float ly = as.y + ad.y; ly = ly >= 0.f ? ly : NEG * ly;
            float lz = as.z + ad.z; lz = lz >= 0.f ? lz : NEG * lz;
            float lw = as.w + ad.w; lw = lw >= 0.f ? lw : NEG * lw;
            w4 = make_float4(__expf(lx), __expf(ly), __expf(lz), __expf(lw));
        }
        sum.x += w4.x; sum.y += w4.y; sum.z += w4.z; sum.w += w4.w;
        *(float4*)&lds_w[wv][lane][0] = w4;
        lds_s[wv][lane] = s;
        __builtin_amdgcn_wave_barrier();

        const int cl = (d - c0) < 64 ? (d - c0) : 64;
        int jj = 0;
        for (; jj + 4 <= cl; jj += 4) {
            int   s0 = lds_s[wv][jj + half];
            int   s1 = lds_s[wv][jj + 2 + half];
            float w0 = lds_w[wv][jj + half][hl];
            float w1 = lds_w[wv][jj + 2 + half][hl];
            uint4 v0 = hp[(size_t)s0 * 32 + l31];
            uint4 v1 = hp[(size_t)s1 * 32 + l31];
            acc[0] = fmaf(w0, bf2f((unsigned short)(v0.x & 0xffff)), acc[0]);
            acc[1] = fmaf(w0, bf2f((unsigned short)(v0.x >> 16)),    acc[1]);
            acc[2] = fmaf(w0, bf2f((unsigned short)(v0.y & 0xffff)), acc[2]);
            acc[3] = fmaf(w0, bf2f((unsigned short)(v0.y >> 16)),    acc[3]);
            acc[4] = fmaf(w0, bf2f((unsigned short)(v0.z & 0xffff)), acc[4]);
            acc[5] = fmaf(w0, bf2f((unsigned short)(v0.z >> 16)),    acc[5]);
            acc[6] = fmaf(w0, bf2f((unsigned short)(v0.w & 0xffff)), acc[6]);
            acc[7] = fmaf(w0, bf2f((unsigned short)(v0.w >> 16)),    acc[7]);
            acc[0] = fmaf(w1, bf2f((unsigned short)(v1.x & 0xffff)), acc[0]);
            acc[1] = fmaf(w1, bf2f((unsigned short)(v1.x >> 16)),    acc[1]);
            acc[2] = fmaf(w1, bf2f((unsigned short)(v1.y & 0xffff)), acc[2]);
            acc[3] = fmaf(w1, bf2f((unsigned short)(v1.y >> 16)),    acc[3]);
            acc[4] = fmaf(w1, bf2f((unsigned short)(v1.z & 0xffff)), acc[4]);
            acc[5] = fmaf(w1, bf2f((unsigned short)(v1.z >> 16)),    acc[5]);
            acc[6] = fmaf(w1, bf2f((unsigned short)(v1.w & 0xffff)), acc[6]);
            acc[7] = fmaf(w1, bf2f((unsigned short)(v1.w >> 16)),    acc[7]);
        }
        for (; jj < cl; jj += 2) {   // tail pair; OOB entries have w=0, s=0
            int   s0 = lds_s[wv][jj + half];
            float w0 = lds_w[wv][jj + half][hl];
            uint4 v0 = hp[(size_t)s0 * 32 + l31];
            acc[0] = fmaf(w0, bf2f((unsigned short)(v0.x & 0xffff)), acc[0]);
            acc[1] = fmaf(w0, bf2f((unsigned short)(v0.x >> 16)),    acc[1]);
            acc[2] = fmaf(w0, bf2f((unsigned short)(v0.y & 0xffff)), acc[2]);
            acc[3] = fmaf(w0, bf2f((unsigned short)(v0.y >> 16)),    acc[3]);
            acc[4] = fmaf(w0, bf2f((unsigned short)(v0.z & 0xffff)), acc[4]);
            acc[5] = fmaf(w0, bf2f((unsigned short)(v0.z >> 16)),    acc[5]);
            acc[6] = fmaf(w0, bf2f((unsigned short)(v0.w & 0xffff)), acc[6]);
            acc[7] = fmaf(w0, bf2f((unsigned short)(v0.w >> 16)),    acc[7]);
        }
        __builtin_amdgcn_wave_barrier();
    }

    // merge halves
#pragma unroll
    for (int k = 0; k < 8; ++k) acc[k] += __shfl_xor(acc[k], 32);

    // denominator reduce
#pragma unroll
    for (int o = 32; o > 0; o >>= 1) {
        sum.x += __shfl_xor(sum.x, o);
        sum.y += __shfl_xor(sum.y, o);
        sum.z += __shfl_xor(sum.z, o);
        sum.w += __shfl_xor(sum.w, o);
    }
    float sh = (hl & 2) ? ((hl & 1) ? sum.w : sum.z) : ((hl & 1) ? sum.y : sum.x);
    float ih = 1.f / (sh + 1e-16f);

    if (half == 0) {
        const float4* bp = (const float4*)bias + l31 * 2;
        float4 b0 = bp[0], b1 = bp[1];
        float4 o0, o1;
        o0.x = fmaxf(fmaf(acc[0], ih, b0.x), 0.f);
        o0.y = fmaxf(fmaf(acc[1], ih, b0.y), 0.f);
        o0.z = fmaxf(fmaf(acc[2], ih, b0.z), 0.f);
        o0.w = fmaxf(fmaf(acc[3], ih, b0.w), 0.f);
        o1.x = fmaxf(fmaf(acc[4], ih, b1.x), 0.f);
        o1.y = fmaxf(fmaf(acc[5], ih, b1.y), 0.f);
        o1.z = fmaxf(fmaf(acc[6], ih, b1.z), 0.f);
        o1.w = fmaxf(fmaf(acc[7], ih, b1.w), 0.f);
        float4* op = (float4*)(out + (size_t)n * 256) + l31 * 2;
        op[0] = o0;
        op[1] = o1;
    }
}

// ---------------------------------------------------------------------------
extern "C" void kernel_launch(void* const* d_in, const int* in_sizes, int n_in,
                              void* d_out, int out_size, void* d_ws, size_t ws_size,
                              hipStream_t stream)
{
    const float* x       = (const float*)d_in[0];
    const int*   ei      = (const int*)d_in[1];
    const float* W       = (const float*)d_in[2];
    const float* att_src = (const float*)d_in[3];
    const float* att_dst = (const float*)d_in[4];
    const float* bias    = (const float*)d_in[5];
    float* out = (float*)d_out;

    const int N = in_sizes[0] / 256;   // 50000
    const int E = in_sizes[1] / 2;     // 800000
    const int tot = E + N;
    const int nb = (N + 1023) / 1024;  // scan blocks (49)

    // workspace carve (~31 MB)
    char* p = (char*)d_ws;
    short* hb      = (short*)p;  p += (size_t)N * 256 * sizeof(short);
    short* Wt      = (short*)p;  p += 256 * 256 * sizeof(short);
    float* a_src_n = (float*)p;  p += (size_t)N * 4 * sizeof(float);
    float* a_dst_n = (float*)p;  p += (size_t)N * 4 * sizeof(float);
    int*   deg     = (int*)p;    p += (size_t)N * sizeof(int);
    int*   off     = (int*)p;    p += (size_t)(N + 1) * sizeof(int);
    int*   cur     = (int*)p;    p += (size_t)N * sizeof(int);
    int*   bsum    = (int*)p;    p += 64 * sizeof(int);
    int*   bexc    = (int*)p;    p += 64 * sizeof(int);
    int*   csr     = (int*)p;

    int prep_items = N > 65536 ? N : 65536;
    prep<<<(prep_items + 255) / 256, 256, 0, stream>>>(W, Wt, deg, N);
    gemm_attn<<<(N + 63) / 64, 256, 0, stream>>>(
        x, Wt, att_src, att_dst, hb, a_src_n, a_dst_n, N);
    hist_kernel<<<(tot + 255) / 256, 256, 0, stream>>>(ei, deg, E, N);
    scan1<<<nb, 1024, 0, stream>>>(deg, off, bsum, N);
    scan2<<<1, 64, 0, stream>>>(bsum, bexc, off, nb, N);
    scan3<<<nb, 1024, 0, stream>>>(off, cur, bexc, N);
    scatter_kernel<<<(tot + 255) / 256, 256, 0, stream>>>(ei, cur, csr, E, N);
    aggregate<<<(N + 3) / 4, 256, 0, stream>>>(hb, a_src_n, a_dst_n, off, csr, bias, out, N);
}

// Round 6
// 276.924 us; speedup vs baseline: 1.1332x; 1.1332x over previous
//
#include <hip/hip_runtime.h>
#include <hip/hip_bf16.h>
#include <math.h>

#define NEG 0.2f
#define BSH 5                 // bucket = dst >> 5  (32 dsts per bucket)
#define EPB 8192              // edges per build block

typedef __attribute__((ext_vector_type(4))) float f4;
typedef __attribute__((ext_vector_type(8))) short s8;

__device__ __forceinline__ short f2bf(float f) {
    unsigned u = __float_as_uint(f);
    u += 0x7fff + ((u >> 16) & 1);          // round-to-nearest-even
    return (short)(u >> 16);
}
__device__ __forceinline__ unsigned pk2(float a, float b) {
    union { __hip_bfloat162 h; unsigned u; } c;
    c.h = __float22bfloat162_rn(make_float2(a, b));   // v_cvt_pk_bf16_f32
    return c.u;
}
__device__ __forceinline__ float bf2f(unsigned short s) {
    return __uint_as_float(((unsigned)s) << 16);
}

// ---------------------------------------------------------------------------
// Kernel 0: prep — Wt[n][k] = bf16(W[k][n])
// ---------------------------------------------------------------------------
__global__ void prep(const float* __restrict__ W, short* __restrict__ Wt)
{
    int id = blockIdx.x * 256 + threadIdx.x;
    int n = id >> 8, k = id & 255;
    Wt[id] = f2bf(W[k * 256 + n]);
}

// ---------------------------------------------------------------------------
// Kernel 1: MFMA GEMM (R3 structure): LDS-staged x, h^T orientation
// D[ch][node]; lane holds 4 contiguous channels of one node.
// Block: 128 ch (grid.y*128 + wc*64 => head) x 128 nodes. 4 waves 2x2.
// ---------------------------------------------------------------------------
__global__ __launch_bounds__(256) void gemm_attn(
    const float* __restrict__ x, const short* __restrict__ Wt,
    const float* __restrict__ att_src, const float* __restrict__ att_dst,
    short* __restrict__ hb, float* __restrict__ a_src_n,
    float* __restrict__ a_dst_n, int M)
{
    __shared__ __align__(16) short xs[128][32];   // node-rows x 32 k (bf16)
    const int t = threadIdx.x;
    const int lane = t & 63, wv = t >> 6;
    const int wr = wv >> 1, wc = wv & 1;          // wr: node half, wc: channel half
    const int quad = lane >> 4, l15 = lane & 15;
    const int n0 = blockIdx.x * 128;              // node base
    const int bn = blockIdx.y;                    // channel block (128 ch)
    const int hd = bn * 2 + wc;                   // head of this wave

    const int row0 = t >> 2, kq0 = t & 3;
    const int row1 = (t + 256) >> 2, kq1 = (t + 256) & 3;
    const bool ok0 = (n0 + row0) < M, ok1 = (n0 + row1) < M;
    const float* xp0 = x + (size_t)(n0 + row0) * 256 + kq0 * 8;
    const float* xp1 = x + (size_t)(n0 + row1) * 256 + kq1 * 8;

    const short* wbase = Wt + (size_t)(bn * 128 + wc * 64 + l15) * 256 + quad * 8;

    f4 acc[4][4];   // [i: ch frag][j: node frag]
#pragma unroll
    for (int i = 0; i < 4; ++i)
#pragma unroll
        for (int j = 0; j < 4; ++j) acc[i][j] = (f4)(0.f);

    for (int ks = 0; ks < 8; ++ks) {
        float4 a0 = {}, a1 = {}, b0 = {}, b1 = {};
        if (ok0) { const float4* p = (const float4*)(xp0 + ks * 32); a0 = p[0]; a1 = p[1]; }
        if (ok1) { const float4* p = (const float4*)(xp1 + ks * 32); b0 = p[0]; b1 = p[1]; }
        __syncthreads();
        uint4 u0 = { pk2(a0.x, a0.y), pk2(a0.z, a0.w), pk2(a1.x, a1.y), pk2(a1.z, a1.w) };
        uint4 u1 = { pk2(b0.x, b0.y), pk2(b0.z, b0.w), pk2(b1.x, b1.y), pk2(b1.z, b1.w) };
        *(uint4*)&xs[row0][kq0 * 8] = u0;
        *(uint4*)&xs[row1][kq1 * 8] = u1;
        __syncthreads();

        s8 af[4], bf[4];
#pragma unroll
        for (int i = 0; i < 4; ++i)
            af[i] = *(const s8*)(wbase + (size_t)(i * 16) * 256 + ks * 32);
#pragma unroll
        for (int j = 0; j < 4; ++j)
            bf[j] = *(const s8*)&xs[wr * 64 + j * 16 + l15][quad * 8];
#pragma unroll
        for (int i = 0; i < 4; ++i)
#pragma unroll
            for (int j = 0; j < 4; ++j)
                acc[i][j] = __builtin_amdgcn_mfma_f32_16x16x32_bf16(af[i], bf[j], acc[i][j], 0, 0, 0);
    }

    float asv[4][4], adv[4][4];
#pragma unroll
    for (int i = 0; i < 4; ++i)
#pragma unroll
        for (int rr = 0; rr < 4; ++rr) {
            asv[i][rr] = att_src[hd * 64 + i * 16 + quad * 4 + rr];
            adv[i][rr] = att_dst[hd * 64 + i * 16 + quad * 4 + rr];
        }

#pragma unroll
    for (int j = 0; j < 4; ++j) {
        const int node = n0 + wr * 64 + j * 16 + l15;
        const bool ok = node < M;
        float ps = 0.f, pd = 0.f;
#pragma unroll
        for (int i = 0; i < 4; ++i)
#pragma unroll
            for (int rr = 0; rr < 4; ++rr) {
                float v = acc[i][j][rr];
                ps = fmaf(v, asv[i][rr], ps);
                pd = fmaf(v, adv[i][rr], pd);
            }
        ps += __shfl_xor(ps, 16); ps += __shfl_xor(ps, 32);
        pd += __shfl_xor(pd, 16); pd += __shfl_xor(pd, 32);
        if (ok && quad == 0) {
            a_src_n[node * 4 + hd] = ps;
            a_dst_n[node * 4 + hd] = pd;
        }
        if (ok) {
#pragma unroll
            for (int i = 0; i < 4; ++i) {
                uint2 pk = make_uint2(pk2(acc[i][j][0], acc[i][j][1]),
                                      pk2(acc[i][j][2], acc[i][j][3]));
                *(uint2*)&hb[(size_t)node * 256 + hd * 64 + i * 16 + quad * 4] = pk;
            }
        }
    }
}

// ---------------------------------------------------------------------------
// Kernel 2: 2D bucket histogram — hist2d[bucket][blk] (NO global atomics;
// each block owns its column). LDS hist per block.
// ---------------------------------------------------------------------------
__global__ __launch_bounds__(256) void count2d(const int* __restrict__ ei,
                                               int* __restrict__ hist2d,
                                               int E, int N, int NBUCK, int NB)
{
    extern __shared__ int lh[];           // NBUCK ints
    const int t = threadIdx.x, blk = blockIdx.x;
    for (int b = t; b < NBUCK; b += 256) lh[b] = 0;
    __syncthreads();
    const int e0 = blk * EPB, Etot = E + N;
#pragma unroll 4
    for (int i = 0; i < EPB / 256; ++i) {
        int e = e0 + i * 256 + t;
        if (e < Etot) {
            int dte = (e < E) ? ei[E + e] : (e - E);
            atomicAdd(&lh[dte >> BSH], 1);
        }
    }
    __syncthreads();
    for (int b = t; b < NBUCK; b += 256) hist2d[b * NB + blk] = lh[b];
}

// ---------------------------------------------------------------------------
// Kernels 3a/3b/3c: exclusive scan of hist2d (Ntot = NBUCK*NB elems) -> scanned
// ---------------------------------------------------------------------------
__global__ __launch_bounds__(1024) void scan1(const int* __restrict__ src,
                                              int* __restrict__ dst,
                                              int* __restrict__ bsum, int Ntot)
{
    __shared__ int wsum[16], wexc[16];
    const int t = threadIdx.x, lane = t & 63, w = t >> 6;
    const int idx = blockIdx.x * 1024 + t;
    int v = (idx < Ntot) ? src[idx] : 0;
    int val = v;
#pragma unroll
    for (int o = 1; o < 64; o <<= 1) {
        int u = __shfl_up(val, o);
        if (lane >= o) val += u;
    }
    if (lane == 63) wsum[w] = val;
    __syncthreads();
    if (t < 16) {
        int s = wsum[t];
#pragma unroll
        for (int o = 1; o < 16; o <<= 1) {
            int u = __shfl_up(s, o, 16);
            if (t >= o) s += u;
        }
        wexc[t] = s - wsum[t];
        if (t == 15) bsum[blockIdx.x] = s;
    }
    __syncthreads();
    if (idx < Ntot) dst[idx] = wexc[w] + val - v;
}

__global__ __launch_bounds__(1024) void scan2v(const int* __restrict__ bsum,
                                               int* __restrict__ bexc,
                                               int* __restrict__ scanned,
                                               int nb, int Ntot)
{
    __shared__ int wsum[16], wexc[16];
    const int t = threadIdx.x, lane = t & 63, w = t >> 6;
    int v = (t < nb) ? bsum[t] : 0;
    int val = v;
#pragma unroll
    for (int o = 1; o < 64; o <<= 1) {
        int u = __shfl_up(val, o);
        if (lane >= o) val += u;
    }
    if (lane == 63) wsum[w] = val;
    __syncthreads();
    if (t < 16) {
        int s = wsum[t];
#pragma unroll
        for (int o = 1; o < 16; o <<= 1) {
            int u = __shfl_up(s, o, 16);
            if (t >= o) s += u;
        }
        wexc[t] = s - wsum[t];
    }
    __syncthreads();
    int excl = wexc[w] + val - v;
    if (t < nb) bexc[t] = excl;
    if (t == nb - 1) scanned[Ntot] = excl + v;   // grand total sentinel
}

__global__ __launch_bounds__(1024) void scan3(int* __restrict__ scanned,
                                              const int* __restrict__ bexc, int Ntot)
{
    int idx = blockIdx.x * 1024 + threadIdx.x;
    if (idx < Ntot) scanned[idx] += bexc[blockIdx.x];
}

// ---------------------------------------------------------------------------
// Kernel 4: bucket scatter — each block's entries per bucket land in
// consecutive global slots (base from scanned column, rank via LDS cursor).
// Entry packed: src | (dst&31)<<20   (src < 2^16 fits).
// ---------------------------------------------------------------------------
__global__ __launch_bounds__(256) void scatter2(const int* __restrict__ ei,
                                                const int* __restrict__ scanned,
                                                unsigned* __restrict__ bucketed,
                                                int E, int N, int NBUCK, int NB)
{
    extern __shared__ int lcur[];          // NBUCK ints
    const int t = threadIdx.x, blk = blockIdx.x;
    for (int b = t; b < NBUCK; b += 256) lcur[b] = scanned[b * NB + blk];
    __syncthreads();
    const int e0 = blk * EPB, Etot = E + N;
#pragma unroll 4
    for (int i = 0; i < EPB / 256; ++i) {
        int e = e0 + i * 256 + t;
        if (e < Etot) {
            int src, dte;
            if (e < E) { src = ei[e]; dte = ei[E + e]; }
            else       { src = e - E; dte = src; }
            int pos = atomicAdd(&lcur[dte >> BSH], 1);
            bucketed[pos] = (unsigned)src | ((unsigned)(dte & 31) << 20);
        }
    }
}

// ---------------------------------------------------------------------------
// Kernel 5: per-bucket aggregate. Block b owns dsts [b*32, b*32+32).
// Stage bucket entries -> LDS, build 32-dst local CSR (LDS atomics),
// then per dst: producer lanes compute unnormalized weights -> LDS,
// two half-waves gather full 512B hb rows (uint4/lane), merge, normalize.
// R6 fix: tail-loop lcsr index is GUARDED (was reading uninitialized LDS
// -> wild 20-bit src -> OOB hb gather -> GPU fault).
// ---------------------------------------------------------------------------
__global__ __launch_bounds__(256) void aggregate2(
    const short* __restrict__ hb, const float* __restrict__ a_src_n,
    const float* __restrict__ a_dst_n, const int* __restrict__ scanned,
    const unsigned* __restrict__ bucketed, const float* __restrict__ bias,
    float* __restrict__ out, int N, int NB)
{
    __shared__ unsigned est[2056];
    __shared__ int lcsr[2056];
    __shared__ int ldeg[32], loff[32], lcur[32];
    __shared__ float lds_w[4][64][4];

    const int t = threadIdx.x, lane = t & 63, wv = t >> 6;
    const int half = lane >> 5, l31 = lane & 31;
    const int hl = l31 >> 3;
    const int b = blockIdx.x;

    const int gbase = scanned[b * NB];
    const int gend  = scanned[(b + 1) * NB];   // b+1==NBUCK hits sentinel
    int cnt = gend - gbase;
    if (cnt > 2048) cnt = 2048;                // safety clamp (never hit: ~545 avg)

    if (t < 32) ldeg[t] = 0;
    // zero the slots reachable by the guarded tail (belt+braces)
    for (int i = cnt + t; i < cnt + 8 && i < 2056; i += 256) lcsr[i] = 0;
    __syncthreads();
    for (int i = t; i < cnt; i += 256) {
        unsigned en = bucketed[gbase + i];
        est[i] = en;
        atomicAdd(&ldeg[en >> 20], 1);
    }
    __syncthreads();
    if (t < 32) {
        int v = ldeg[t], val = v;
#pragma unroll
        for (int o = 1; o < 32; o <<= 1) {
            int u = __shfl_up(val, o, 32);
            if (t >= o) val += u;
        }
        loff[t] = val - v;
        lcur[t] = val - v;
    }
    __syncthreads();
    for (int i = t; i < cnt; i += 256) {
        unsigned en = est[i];
        int pos = atomicAdd(&lcur[en >> 20], 1);
        lcsr[pos] = en & 0xFFFFF;
    }
    __syncthreads();

    const uint4* hp = (const uint4*)hb;
    const float4* bp = (const float4*)bias + l31 * 2;
    float4 b0 = bp[0], b1 = bp[1];

    for (int ld = wv; ld < 32; ld += 4) {
        const int n = (b << BSH) + ld;
        if (n >= N) continue;                  // wave-uniform
        const int base = loff[ld];
        const int d = ldeg[ld];
        const float4 ad = *(const float4*)(a_dst_n + 4 * n);

        float acc[8] = {0.f, 0.f, 0.f, 0.f, 0.f, 0.f, 0.f, 0.f};
        float4 sum = make_float4(0.f, 0.f, 0.f, 0.f);

        for (int c0 = 0; c0 < d; c0 += 64) {
            int j = c0 + lane;
            float4 w4 = make_float4(0.f, 0.f, 0.f, 0.f);
            if (j < d) {
                int s = lcsr[base + j];
                float4 as = *(const float4*)(a_src_n + 4 * s);
                float lx = as.x + ad.x; lx = lx >= 0.f ? lx : NEG * lx;
                float ly = as.y + ad.y; ly = ly >= 0.f ? ly : NEG * ly;
                float lz = as.z + ad.z; lz = lz >= 0.f ? lz : NEG * lz;
                float lw = as.w + ad.w; lw = lw >= 0.f ? lw : NEG * lw;
                w4 = make_float4(__expf(lx), __expf(ly), __expf(lz), __expf(lw));
            }
            sum.x += w4.x; sum.y += w4.y; sum.z += w4.z; sum.w += w4.w;
            *(float4*)&lds_w[wv][lane][0] = w4;
            __builtin_amdgcn_wave_barrier();

            const int cl = (d - c0) < 64 ? (d - c0) : 64;
            int jj = 0;
            for (; jj + 4 <= cl; jj += 4) {
                int   s0 = lcsr[base + c0 + jj + half];
                int   s1 = lcsr[base + c0 + jj + 2 + half];
                float w0 = lds_w[wv][jj + half][hl];
                float w1 = lds_w[wv][jj + 2 + half][hl];
                uint4 v0 = hp[(size_t)s0 * 32 + l31];
                uint4 v1 = hp[(size_t)s1 * 32 + l31];
                acc[0] = fmaf(w0, bf2f((unsigned short)(v0.x & 0xffff)), acc[0]);
                acc[1] = fmaf(w0, bf2f((unsigned short)(v0.x >> 16)),    acc[1]);
                acc[2] = fmaf(w0, bf2f((unsigned short)(v0.y & 0xffff)), acc[2]);
                acc[3] = fmaf(w0, bf2f((unsigned short)(v0.y >> 16)),    acc[3]);
                acc[4] = fmaf(w0, bf2f((unsigned short)(v0.z & 0xffff)), acc[4]);
                acc[5] = fmaf(w0, bf2f((unsigned short)(v0.z >> 16)),    acc[5]);
                acc[6] = fmaf(w0, bf2f((unsigned short)(v0.w & 0xffff)), acc[6]);
                acc[7] = fmaf(w0, bf2f((unsigned short)(v0.w >> 16)),    acc[7]);
                acc[0] = fmaf(w1, bf2f((unsigned short)(v1.x & 0xffff)), acc[0]);
                acc[1] = fmaf(w1, bf2f((unsigned short)(v1.x >> 16)),    acc[1]);
                acc[2] = fmaf(w1, bf2f((unsigned short)(v1.y & 0xffff)), acc[2]);
                acc[3] = fmaf(w1, bf2f((unsigned short)(v1.y >> 16)),    acc[3]);
                acc[4] = fmaf(w1, bf2f((unsigned short)(v1.z & 0xffff)), acc[4]);
                acc[5] = fmaf(w1, bf2f((unsigned short)(v1.z >> 16)),    acc[5]);
                acc[6] = fmaf(w1, bf2f((unsigned short)(v1.w & 0xffff)), acc[6]);
                acc[7] = fmaf(w1, bf2f((unsigned short)(v1.w >> 16)),    acc[7]);
            }
            if (jj < cl) {                      // guarded tail (1..3 entries)
                int  ii  = jj + half;           // may equal cl -> masked
                bool okt = ii < cl;
                int  iic = okt ? ii : 0;
                int   s0 = lcsr[base + c0 + iic];
                float w0 = okt ? lds_w[wv][iic][hl] : 0.f;
                uint4 v0 = hp[(size_t)s0 * 32 + l31];
                acc[0] = fmaf(w0, bf2f((unsigned short)(v0.x & 0xffff)), acc[0]);
                acc[1] = fmaf(w0, bf2f((unsigned short)(v0.x >> 16)),    acc[1]);
                acc[2] = fmaf(w0, bf2f((unsigned short)(v0.y & 0xffff)), acc[2]);
                acc[3] = fmaf(w0, bf2f((unsigned short)(v0.y >> 16)),    acc[3]);
                acc[4] = fmaf(w0, bf2f((unsigned short)(v0.z & 0xffff)), acc[4]);
                acc[5] = fmaf(w0, bf2f((unsigned short)(v0.z >> 16)),    acc[5]);
                acc[6] = fmaf(w0, bf2f((unsigned short)(v0.w & 0xffff)), acc[6]);
                acc[7] = fmaf(w0, bf2f((unsigned short)(v0.w >> 16)),    acc[7]);
                jj += 2;
                if (jj < cl) {                  // at most one more pair
                    int  i2  = jj + half;
                    bool ok2 = i2 < cl;
                    int  i2c = ok2 ? i2 : 0;
                    int   s1 = lcsr[base + c0 + i2c];
                    float w1 = ok2 ? lds_w[wv][i2c][hl] : 0.f;
                    uint4 v1 = hp[(size_t)s1 * 32 + l31];
                    acc[0] = fmaf(w1, bf2f((unsigned short)(v1.x & 0xffff)), acc[0]);
                    acc[1] = fmaf(w1, bf2f((unsigned short)(v1.x >> 16)),    acc[1]);
                    acc[2] = fmaf(w1, bf2f((unsigned short)(v1.y & 0xffff)), acc[2]);
                    acc[3] = fmaf(w1, bf2f((unsigned short)(v1.y >> 16)),    acc[3]);
                    acc[4] = fmaf(w1, bf2f((unsigned short)(v1.z & 0xffff)), acc[4]);
                    acc[5] = fmaf(w1, bf2f((unsigned short)(v1.z >> 16)),    acc[5]);
                    acc[6] = fmaf(w1, bf2f((unsigned short)(v1.w & 0xffff)), acc[6]);
                    acc[7] = fmaf(w1, bf2f((unsigned short)(v1.w >> 16)),    acc[7]);
                }
            }
            __builtin_amdgcn_wave_barrier();
        }

#pragma unroll
        for (int k = 0; k < 8; ++k) acc[k] += __shfl_xor(acc[k], 32);

#pragma unroll
        for (int o = 32; o > 0; o >>= 1) {
            sum.x += __shfl_xor(sum.x, o);
            sum.y += __shfl_xor(sum.y, o);
            sum.z += __shfl_xor(sum.z, o);
            sum.w += __shfl_xor(sum.w, o);
        }
        float sh = (hl & 2) ? ((hl & 1) ? sum.w : sum.z) : ((hl & 1) ? sum.y : sum.x);
        float ih = 1.f / (sh + 1e-16f);

        if (half == 0) {
            float4 o0, o1;
            o0.x = fmaxf(fmaf(acc[0], ih, b0.x), 0.f);
            o0.y = fmaxf(fmaf(acc[1], ih, b0.y), 0.f);
            o0.z = fmaxf(fmaf(acc[2], ih, b0.z), 0.f);
            o0.w = fmaxf(fmaf(acc[3], ih, b0.w), 0.f);
            o1.x = fmaxf(fmaf(acc[4], ih, b1.x), 0.f);
            o1.y = fmaxf(fmaf(acc[5], ih, b1.y), 0.f);
            o1.z = fmaxf(fmaf(acc[6], ih, b1.z), 0.f);
            o1.w = fmaxf(fmaf(acc[7], ih, b1.w), 0.f);
            float4* op = (float4*)(out + (size_t)n * 256) + l31 * 2;
            op[0] = o0;
            op[1] = o1;
        }
    }
}

// ---------------------------------------------------------------------------
extern "C" void kernel_launch(void* const* d_in, const int* in_sizes, int n_in,
                              void* d_out, int out_size, void* d_ws, size_t ws_size,
                              hipStream_t stream)
{
    const float* x       = (const float*)d_in[0];
    const int*   ei      = (const int*)d_in[1];
    const float* W       = (const float*)d_in[2];
    const float* att_src = (const float*)d_in[3];
    const float* att_dst = (const float*)d_in[4];
    const float* bias    = (const float*)d_in[5];
    float* out = (float*)d_out;

    const int N = in_sizes[0] / 256;       // 50000
    const int E = in_sizes[1] / 2;         // 800000
    const int Etot = E + N;                // 850000
    const int NBUCK = (N + 31) >> BSH;     // 1563
    const int NB = (Etot + EPB - 1) / EPB; // 104
    const int Ntot = NBUCK * NB;           // 162552
    const int nb1 = (Ntot + 1023) / 1024;  // 159

    // workspace carve (~32 MB; ws proven >= 56 MB in R1)
    char* p = (char*)d_ws;
    short*    hb      = (short*)p;    p += (size_t)N * 256 * sizeof(short);
    short*    Wt      = (short*)p;    p += 256 * 256 * sizeof(short);
    float*    a_src_n = (float*)p;    p += (size_t)N * 4 * sizeof(float);
    float*    a_dst_n = (float*)p;    p += (size_t)N * 4 * sizeof(float);
    int*      hist2d  = (int*)p;      p += (size_t)(Ntot + 1) * sizeof(int);
    int*      scanned = (int*)p;      p += (size_t)(Ntot + 1) * sizeof(int);
    int*      bsum    = (int*)p;      p += 1024 * sizeof(int);
    int*      bexc    = (int*)p;      p += 1024 * sizeof(int);
    unsigned* bucketed= (unsigned*)p; p += (size_t)Etot * sizeof(unsigned);

    prep<<<256, 256, 0, stream>>>(W, Wt);
    gemm_attn<<<dim3((N + 127) / 128, 2), 256, 0, stream>>>(
        x, Wt, att_src, att_dst, hb, a_src_n, a_dst_n, N);
    count2d<<<NB, 256, NBUCK * sizeof(int), stream>>>(ei, hist2d, E, N, NBUCK, NB);
    scan1<<<nb1, 1024, 0, stream>>>(hist2d, scanned, bsum, Ntot);
    scan2v<<<1, 1024, 0, stream>>>(bsum, bexc, scanned, nb1, Ntot);
    scan3<<<nb1, 1024, 0, stream>>>(scanned, bexc, Ntot);
    scatter2<<<NB, 256, NBUCK * sizeof(int), stream>>>(ei, scanned, bucketed, E, N, NBUCK, NB);
    aggregate2<<<NBUCK, 256, 0, stream>>>(hb, a_src_n, a_dst_n, scanned, bucketed,
                                          bias, out, N, NB);
}

// Round 7
// 255.487 us; speedup vs baseline: 1.2283x; 1.0839x over previous
//
#include <hip/hip_runtime.h>
#include <hip/hip_bf16.h>
#include <math.h>

#define NEG 0.2f
#define BSH 5                 // bucket = dst >> 5  (32 dsts per bucket)
#define EPB 8192              // edges per build block

typedef __attribute__((ext_vector_type(4))) float f4;
typedef __attribute__((ext_vector_type(8))) short s8;

__device__ __forceinline__ short f2bf(float f) {
    unsigned u = __float_as_uint(f);
    u += 0x7fff + ((u >> 16) & 1);          // round-to-nearest-even
    return (short)(u >> 16);
}
__device__ __forceinline__ unsigned pk2(float a, float b) {
    union { __hip_bfloat162 h; unsigned u; } c;
    c.h = __float22bfloat162_rn(make_float2(a, b));   // v_cvt_pk_bf16_f32
    return c.u;
}
__device__ __forceinline__ float bf2f(unsigned short s) {
    return __uint_as_float(((unsigned)s) << 16);
}

// ---------------------------------------------------------------------------
// Kernel 0: prep — Wt[n][k] = bf16(W[k][n]); also off[N] sentinel.
// ---------------------------------------------------------------------------
__global__ void prep(const float* __restrict__ W, short* __restrict__ Wt,
                     int* __restrict__ off, int N, int Etot)
{
    int id = blockIdx.x * 256 + threadIdx.x;
    int n = id >> 8, k = id & 255;
    Wt[id] = f2bf(W[k * 256 + n]);
    if (id == 0) off[N] = Etot;
}

// ---------------------------------------------------------------------------
// Kernel 1: MFMA GEMM, single-pass x. 512 threads = 8 waves
// (2 node-halves x 4 heads). Block: 256 ch x 128 nodes. h^T layout
// D[ch][node]; lane holds 4 contiguous channels of one node.
// ---------------------------------------------------------------------------
__global__ __launch_bounds__(512) void gemm_attn(
    const float* __restrict__ x, const short* __restrict__ Wt,
    const float* __restrict__ att_src, const float* __restrict__ att_dst,
    short* __restrict__ hb, float* __restrict__ a_src_n,
    float* __restrict__ a_dst_n, int M)
{
    __shared__ __align__(16) short xs[128][32];   // node-rows x 32 k (bf16)
    const int t = threadIdx.x;
    const int lane = t & 63, wv = t >> 6;
    const int wr = wv >> 2;                       // node half
    const int hd = wv & 3;                        // head (64 channels)
    const int quad = lane >> 4, l15 = lane & 15;
    const int n0 = blockIdx.x * 128;

    const int row = t >> 2, kq = t & 3;           // 512 threads cover 128x32
    const bool okr = (n0 + row) < M;
    const float* xp = x + (size_t)(n0 + row) * 256 + kq * 8;

    const short* wbase = Wt + (size_t)(hd * 64 + l15) * 256 + quad * 8;

    f4 acc[4][4];   // [i: ch frag][j: node frag]
#pragma unroll
    for (int i = 0; i < 4; ++i)
#pragma unroll
        for (int j = 0; j < 4; ++j) acc[i][j] = (f4)(0.f);

    for (int ks = 0; ks < 8; ++ks) {
        float4 v0 = {}, v1 = {};
        if (okr) { const float4* p = (const float4*)(xp + ks * 32); v0 = p[0]; v1 = p[1]; }
        __syncthreads();
        uint4 u = { pk2(v0.x, v0.y), pk2(v0.z, v0.w), pk2(v1.x, v1.y), pk2(v1.z, v1.w) };
        *(uint4*)&xs[row][kq * 8] = u;
        __syncthreads();

        s8 af[4], bf[4];
#pragma unroll
        for (int i = 0; i < 4; ++i)
            af[i] = *(const s8*)(wbase + (size_t)(i * 16) * 256 + ks * 32);
#pragma unroll
        for (int j = 0; j < 4; ++j)
            bf[j] = *(const s8*)&xs[wr * 64 + j * 16 + l15][quad * 8];
#pragma unroll
        for (int i = 0; i < 4; ++i)
#pragma unroll
            for (int j = 0; j < 4; ++j)
                acc[i][j] = __builtin_amdgcn_mfma_f32_16x16x32_bf16(af[i], bf[j], acc[i][j], 0, 0, 0);
    }

    float asv[4][4], adv[4][4];
#pragma unroll
    for (int i = 0; i < 4; ++i)
#pragma unroll
        for (int rr = 0; rr < 4; ++rr) {
            asv[i][rr] = att_src[hd * 64 + i * 16 + quad * 4 + rr];
            adv[i][rr] = att_dst[hd * 64 + i * 16 + quad * 4 + rr];
        }

#pragma unroll
    for (int j = 0; j < 4; ++j) {
        const int node = n0 + wr * 64 + j * 16 + l15;
        const bool ok = node < M;
        float ps = 0.f, pd = 0.f;
#pragma unroll
        for (int i = 0; i < 4; ++i)
#pragma unroll
            for (int rr = 0; rr < 4; ++rr) {
                float v = acc[i][j][rr];
                ps = fmaf(v, asv[i][rr], ps);
                pd = fmaf(v, adv[i][rr], pd);
            }
        ps += __shfl_xor(ps, 16); ps += __shfl_xor(ps, 32);
        pd += __shfl_xor(pd, 16); pd += __shfl_xor(pd, 32);
        if (ok && quad == 0) {
            a_src_n[node * 4 + hd] = ps;
            a_dst_n[node * 4 + hd] = pd;
        }
        if (ok) {
#pragma unroll
            for (int i = 0; i < 4; ++i) {
                uint2 pk = make_uint2(pk2(acc[i][j][0], acc[i][j][1]),
                                      pk2(acc[i][j][2], acc[i][j][3]));
                *(uint2*)&hb[(size_t)node * 256 + hd * 64 + i * 16 + quad * 4] = pk;
            }
        }
    }
}

// ---------------------------------------------------------------------------
// Kernel 2: 2D bucket histogram — hist2d[bucket][blk] (no global atomics)
// ---------------------------------------------------------------------------
__global__ __launch_bounds__(256) void count2d(const int* __restrict__ ei,
                                               int* __restrict__ hist2d,
                                               int E, int N, int NBUCK, int NB)
{
    extern __shared__ int lh[];           // NBUCK ints
    const int t = threadIdx.x, blk = blockIdx.x;
    for (int b = t; b < NBUCK; b += 256) lh[b] = 0;
    __syncthreads();
    const int e0 = blk * EPB, Etot = E + N;
#pragma unroll 4
    for (int i = 0; i < EPB / 256; ++i) {
        int e = e0 + i * 256 + t;
        if (e < Etot) {
            int dte = (e < E) ? ei[E + e] : (e - E);
            atomicAdd(&lh[dte >> BSH], 1);
        }
    }
    __syncthreads();
    for (int b = t; b < NBUCK; b += 256) hist2d[b * NB + blk] = lh[b];
}

// ---------------------------------------------------------------------------
// Kernels 3a/3b: two-level exclusive scan of hist2d (Ntot elems).
// Final value of element idx = scanned[idx] + bexc[idx>>10] (applied by
// consumers inline; no scan3 pass).
// ---------------------------------------------------------------------------
__global__ __launch_bounds__(1024) void scan1(const int* __restrict__ src,
                                              int* __restrict__ dst,
                                              int* __restrict__ bsum, int Ntot)
{
    __shared__ int wsum[16], wexc[16];
    const int t = threadIdx.x, lane = t & 63, w = t >> 6;
    const int idx = blockIdx.x * 1024 + t;
    int v = (idx < Ntot) ? src[idx] : 0;
    int val = v;
#pragma unroll
    for (int o = 1; o < 64; o <<= 1) {
        int u = __shfl_up(val, o);
        if (lane >= o) val += u;
    }
    if (lane == 63) wsum[w] = val;
    __syncthreads();
    if (t < 16) {
        int s = wsum[t];
#pragma unroll
        for (int o = 1; o < 16; o <<= 1) {
            int u = __shfl_up(s, o, 16);
            if (t >= o) s += u;
        }
        wexc[t] = s - wsum[t];
        if (t == 15) bsum[blockIdx.x] = s;
    }
    __syncthreads();
    if (idx < Ntot) dst[idx] = wexc[w] + val - v;
}

__global__ __launch_bounds__(1024) void scan2v(const int* __restrict__ bsum,
                                               int* __restrict__ bexc, int nb)
{
    __shared__ int wsum[16], wexc[16];
    const int t = threadIdx.x, lane = t & 63, w = t >> 6;
    int v = (t < nb) ? bsum[t] : 0;
    int val = v;
#pragma unroll
    for (int o = 1; o < 64; o <<= 1) {
        int u = __shfl_up(val, o);
        if (lane >= o) val += u;
    }
    if (lane == 63) wsum[w] = val;
    __syncthreads();
    if (t < 16) {
        int s = wsum[t];
#pragma unroll
        for (int o = 1; o < 16; o <<= 1) {
            int u = __shfl_up(s, o, 16);
            if (t >= o) s += u;
        }
        wexc[t] = s - wsum[t];
    }
    __syncthreads();
    if (t < nb) bexc[t] = wexc[w] + val - v;
}

// ---------------------------------------------------------------------------
// Kernel 4: bucket scatter (bexc applied inline)
// Entry packed: src | (dst&31)<<20
// ---------------------------------------------------------------------------
__global__ __launch_bounds__(256) void scatter2(const int* __restrict__ ei,
                                                const int* __restrict__ scanned,
                                                const int* __restrict__ bexc,
                                                unsigned* __restrict__ bucketed,
                                                int E, int N, int NBUCK, int NB)
{
    extern __shared__ int lcur[];          // NBUCK ints
    const int t = threadIdx.x, blk = blockIdx.x;
    for (int b = t; b < NBUCK; b += 256) {
        int idx = b * NB + blk;
        lcur[b] = scanned[idx] + bexc[idx >> 10];
    }
    __syncthreads();
    const int e0 = blk * EPB, Etot = E + N;
#pragma unroll 4
    for (int i = 0; i < EPB / 256; ++i) {
        int e = e0 + i * 256 + t;
        if (e < Etot) {
            int src, dte;
            if (e < E) { src = ei[e]; dte = ei[E + e]; }
            else       { src = e - E; dte = src; }
            int pos = atomicAdd(&lcur[dte >> BSH], 1);
            bucketed[pos] = (unsigned)src | ((unsigned)(dte & 31) << 20);
        }
    }
}

// ---------------------------------------------------------------------------
// Kernel 5: csr_build — one block per bucket: group the bucket's entries by
// dst into global csr (dst-sorted) + off[n]. LDS-atomic contention lives
// here (tiny kernel), NOT in the gather kernel.
// ---------------------------------------------------------------------------
__global__ __launch_bounds__(256) void csr_build(
    const unsigned* __restrict__ bucketed, const int* __restrict__ scanned,
    const int* __restrict__ bexc, int* __restrict__ off, int* __restrict__ csr,
    int N, int NB, int NBUCK, int Etot)
{
    __shared__ unsigned est[2048];
    __shared__ int ldeg[32], loff[32], lcur[32];
    const int t = threadIdx.x, b = blockIdx.x;

    const int i0 = b * NB;
    const int gbase = scanned[i0] + bexc[i0 >> 10];
    int gend;
    if (b + 1 == NBUCK) gend = Etot;
    else { int i1 = (b + 1) * NB; gend = scanned[i1] + bexc[i1 >> 10]; }
    int cnt = gend - gbase;
    if (cnt > 2048) cnt = 2048;            // never hit (~545 avg, ~650 max)

    if (t < 32) ldeg[t] = 0;
    __syncthreads();
    for (int i = t; i < cnt; i += 256) {
        unsigned en = bucketed[gbase + i];
        est[i] = en;
        atomicAdd(&ldeg[en >> 20], 1);
    }
    __syncthreads();
    if (t < 32) {
        int v = ldeg[t], val = v;
#pragma unroll
        for (int o = 1; o < 32; o <<= 1) {
            int u = __shfl_up(val, o, 32);
            if (t >= o) val += u;
        }
        loff[t] = val - v;
        lcur[t] = val - v;
    }
    __syncthreads();
    for (int i = t; i < cnt; i += 256) {
        unsigned en = est[i];
        int pos = atomicAdd(&lcur[en >> 20], 1);
        csr[gbase + pos] = (int)(en & 0xFFFFF);
    }
    if (t < 32) {
        int n = (b << BSH) + t;
        if (n < N) off[n] = gbase + loff[t];
    }
}

// ---------------------------------------------------------------------------
// Kernel 6: aggregate (R4 structure, zero LDS conflicts). One wave per dst.
// Producer: lane j -> unnormalized weight (4 heads) + src id into LDS.
// Consumer: two half-waves gather full 512B hb rows (uint4/lane), 2x
// unrolled; halves merged via shfl_xor(32); normalize once at end.
// ---------------------------------------------------------------------------
__global__ __launch_bounds__(256) void aggregate(const short* __restrict__ hb,
                                                 const float* __restrict__ a_src_n,
                                                 const float* __restrict__ a_dst_n,
                                                 const int* __restrict__ off,
                                                 const int* __restrict__ csr,
                                                 const float* __restrict__ bias,
                                                 float* __restrict__ out, int N)
{
    __shared__ float lds_w[4][64][4];
    __shared__ int   lds_s[4][64];
    const int wv = threadIdx.x >> 6;
    const int lane = threadIdx.x & 63;
    const int half = lane >> 5, l31 = lane & 31;
    const int n = blockIdx.x * 4 + wv;
    if (n >= N) return;

    const int base = off[n];
    const int d = off[n + 1] - base;
    const float4 ad = *(const float4*)(a_dst_n + 4 * n);
    const int hl = l31 >> 3;             // head of this lane's 8 channels

    float acc[8] = {0.f, 0.f, 0.f, 0.f, 0.f, 0.f, 0.f, 0.f};
    float4 sum = make_float4(0.f, 0.f, 0.f, 0.f);
    const uint4* hp = (const uint4*)hb;

    for (int c0 = 0; c0 < d; c0 += 64) {
        int j = c0 + lane;
        int s = 0;
        float4 w4 = make_float4(0.f, 0.f, 0.f, 0.f);
        if (j < d) {
            s = csr[base + j];
            float4 as = *(const float4*)(a_src_n + 4 * s);
            float lx = as.x + ad.x; lx = lx >= 0.f ? lx : NEG * lx;
            float ly = as.y + ad.y; ly = ly >= 0.f ? ly : NEG * ly;
            float lz = as.z + ad.z; lz = lz >= 0.f ? lz : NEG * lz;
            float lw = as.w + ad.w; lw = lw >= 0.f ? lw : NEG * lw;
            w4 = make_float4(__expf(lx), __expf(ly), __expf(lz), __expf(lw));
        }
        sum.x += w4.x; sum.y += w4.y; sum.z += w4.z; sum.w += w4.w;
        *(float4*)&lds_w[wv][lane][0] = w4;
        lds_s[wv][lane] = s;
        __builtin_amdgcn_wave_barrier();

        const int cl = (d - c0) < 64 ? (d - c0) : 64;
        int jj = 0;
        for (; jj + 4 <= cl; jj += 4) {
            int   s0 = lds_s[wv][jj + half];
            int   s1 = lds_s[wv][jj + 2 + half];
            float w0 = lds_w[wv][jj + half][hl];
            float w1 = lds_w[wv][jj + 2 + half][hl];
            uint4 v0 = hp[(size_t)s0 * 32 + l31];
            uint4 v1 = hp[(size_t)s1 * 32 + l31];
            acc[0] = fmaf(w0, bf2f((unsigned short)(v0.x & 0xffff)), acc[0]);
            acc[1] = fmaf(w0, bf2f((unsigned short)(v0.x >> 16)),    acc[1]);
            acc[2] = fmaf(w0, bf2f((unsigned short)(v0.y & 0xffff)), acc[2]);
            acc[3] = fmaf(w0, bf2f((unsigned short)(v0.y >> 16)),    acc[3]);
            acc[4] = fmaf(w0, bf2f((unsigned short)(v0.z & 0xffff)), acc[4]);
            acc[5] = fmaf(w0, bf2f((unsigned short)(v0.z >> 16)),    acc[5]);
            acc[6] = fmaf(w0, bf2f((unsigned short)(v0.w & 0xffff)), acc[6]);
            acc[7] = fmaf(w0, bf2f((unsigned short)(v0.w >> 16)),    acc[7]);
            acc[0] = fmaf(w1, bf2f((unsigned short)(v1.x & 0xffff)), acc[0]);
            acc[1] = fmaf(w1, bf2f((unsigned short)(v1.x >> 16)),    acc[1]);
            acc[2] = fmaf(w1, bf2f((unsigned short)(v1.y & 0xffff)), acc[2]);
            acc[3] = fmaf(w1, bf2f((unsigned short)(v1.y >> 16)),    acc[3]);
            acc[4] = fmaf(w1, bf2f((unsigned short)(v1.z & 0xffff)), acc[4]);
            acc[5] = fmaf(w1, bf2f((unsigned short)(v1.z >> 16)),    acc[5]);
            acc[6] = fmaf(w1, bf2f((unsigned short)(v1.w & 0xffff)), acc[6]);
            acc[7] = fmaf(w1, bf2f((unsigned short)(v1.w >> 16)),    acc[7]);
        }
        for (; jj < cl; jj += 2) {   // tail: lds_s/lds_w initialized for all 64
            int   s0 = lds_s[wv][jj + half];
            float w0 = lds_w[wv][jj + half][hl];
            uint4 v0 = hp[(size_t)s0 * 32 + l31];
            acc[0] = fmaf(w0, bf2f((unsigned short)(v0.x & 0xffff)), acc[0]);
            acc[1] = fmaf(w0, bf2f((unsigned short)(v0.x >> 16)),    acc[1]);
            acc[2] = fmaf(w0, bf2f((unsigned short)(v0.y & 0xffff)), acc[2]);
            acc[3] = fmaf(w0, bf2f((unsigned short)(v0.y >> 16)),    acc[3]);
            acc[4] = fmaf(w0, bf2f((unsigned short)(v0.z & 0xffff)), acc[4]);
            acc[5] = fmaf(w0, bf2f((unsigned short)(v0.z >> 16)),    acc[5]);
            acc[6] = fmaf(w0, bf2f((unsigned short)(v0.w & 0xffff)), acc[6]);
            acc[7] = fmaf(w0, bf2f((unsigned short)(v0.w >> 16)),    acc[7]);
        }
        __builtin_amdgcn_wave_barrier();
    }

#pragma unroll
    for (int k = 0; k < 8; ++k) acc[k] += __shfl_xor(acc[k], 32);

#pragma unroll
    for (int o = 32; o > 0; o >>= 1) {
        sum.x += __shfl_xor(sum.x, o);
        sum.y += __shfl_xor(sum.y, o);
        sum.z += __shfl_xor(sum.z, o);
        sum.w += __shfl_xor(sum.w, o);
    }
    float sh = (hl & 2) ? ((hl & 1) ? sum.w : sum.z) : ((hl & 1) ? sum.y : sum.x);
    float ih = 1.f / (sh + 1e-16f);

    if (half == 0) {
        const float4* bp = (const float4*)bias + l31 * 2;
        float4 b0 = bp[0], b1 = bp[1];
        float4 o0, o1;
        o0.x = fmaxf(fmaf(acc[0], ih, b0.x), 0.f);
        o0.y = fmaxf(fmaf(acc[1], ih, b0.y), 0.f);
        o0.z = fmaxf(fmaf(acc[2], ih, b0.z), 0.f);
        o0.w = fmaxf(fmaf(acc[3], ih, b0.w), 0.f);
        o1.x = fmaxf(fmaf(acc[4], ih, b1.x), 0.f);
        o1.y = fmaxf(fmaf(acc[5], ih, b1.y), 0.f);
        o1.z = fmaxf(fmaf(acc[6], ih, b1.z), 0.f);
        o1.w = fmaxf(fmaf(acc[7], ih, b1.w), 0.f);
        float4* op = (float4*)(out + (size_t)n * 256) + l31 * 2;
        op[0] = o0;
        op[1] = o1;
    }
}

// ---------------------------------------------------------------------------
extern "C" void kernel_launch(void* const* d_in, const int* in_sizes, int n_in,
                              void* d_out, int out_size, void* d_ws, size_t ws_size,
                              hipStream_t stream)
{
    const float* x       = (const float*)d_in[0];
    const int*   ei      = (const int*)d_in[1];
    const float* W       = (const float*)d_in[2];
    const float* att_src = (const float*)d_in[3];
    const float* att_dst = (const float*)d_in[4];
    const float* bias    = (const float*)d_in[5];
    float* out = (float*)d_out;

    const int N = in_sizes[0] / 256;       // 50000
    const int E = in_sizes[1] / 2;         // 800000
    const int Etot = E + N;                // 850000
    const int NBUCK = (N + 31) >> BSH;     // 1563
    const int NB = (Etot + EPB - 1) / EPB; // 104
    const int Ntot = NBUCK * NB;           // 162552
    const int nb1 = (Ntot + 1023) / 1024;  // 159

    // workspace carve (~37 MB; ws >= 56 MB)
    char* p = (char*)d_ws;
    short*    hb      = (short*)p;    p += (size_t)N * 256 * sizeof(short);
    short*    Wt      = (short*)p;    p += 256 * 256 * sizeof(short);
    float*    a_src_n = (float*)p;    p += (size_t)N * 4 * sizeof(float);
    float*    a_dst_n = (float*)p;    p += (size_t)N * 4 * sizeof(float);
    int*      hist2d  = (int*)p;      p += (size_t)Ntot * sizeof(int);
    int*      scanned = (int*)p;      p += (size_t)Ntot * sizeof(int);
    int*      bsum    = (int*)p;      p += 1024 * sizeof(int);
    int*      bexc    = (int*)p;      p += 1024 * sizeof(int);
    int*      off     = (int*)p;      p += (size_t)(N + 1) * sizeof(int);
    unsigned* bucketed= (unsigned*)p; p += (size_t)Etot * sizeof(unsigned);
    int*      csr     = (int*)p;      p += (size_t)Etot * sizeof(int);

    prep<<<256, 256, 0, stream>>>(W, Wt, off, N, Etot);
    gemm_attn<<<(N + 127) / 128, 512, 0, stream>>>(
        x, Wt, att_src, att_dst, hb, a_src_n, a_dst_n, N);
    count2d<<<NB, 256, NBUCK * sizeof(int), stream>>>(ei, hist2d, E, N, NBUCK, NB);
    scan1<<<nb1, 1024, 0, stream>>>(hist2d, scanned, bsum, Ntot);
    scan2v<<<1, 1024, 0, stream>>>(bsum, bexc, nb1);
    scatter2<<<NB, 256, NBUCK * sizeof(int), stream>>>(ei, scanned, bexc, bucketed,
                                                       E, N, NBUCK, NB);
    csr_build<<<NBUCK, 256, 0, stream>>>(bucketed, scanned, bexc, off, csr,
                                         N, NB, NBUCK, Etot);
    aggregate<<<(N + 3) / 4, 256, 0, stream>>>(hb, a_src_n, a_dst_n, off, csr,
                                               bias, out, N);
}

// Round 8
// 233.226 us; speedup vs baseline: 1.3455x; 1.0954x over previous
//
#include <hip/hip_runtime.h>
#include <hip/hip_bf16.h>
#include <math.h>

#define NEG 0.2f
#define BSH 5                 // bucket = dst >> 5  (32 dsts per bucket)
#define EPB 2048              // edges per build block (416 blocks)

typedef __attribute__((ext_vector_type(4))) float f4;
typedef __attribute__((ext_vector_type(8))) short s8;

__device__ __forceinline__ short f2bf(float f) {
    unsigned u = __float_as_uint(f);
    u += 0x7fff + ((u >> 16) & 1);          // round-to-nearest-even
    return (short)(u >> 16);
}
__device__ __forceinline__ unsigned pk2(float a, float b) {
    union { __hip_bfloat162 h; unsigned u; } c;
    c.h = __float22bfloat162_rn(make_float2(a, b));   // v_cvt_pk_bf16_f32
    return c.u;
}
__device__ __forceinline__ float bf2f(unsigned short s) {
    return __uint_as_float(((unsigned)s) << 16);
}

// ---------------------------------------------------------------------------
// Kernel 0: prep_count — blocks [0,256): Wt[n][k]=bf16(W[k][n]) + off[N];
// blocks [256, 256+NB): 2D bucket histogram hist2d[bucket][blk]
// (no global atomics; int4 edge loads on the fast path).
// ---------------------------------------------------------------------------
__global__ __launch_bounds__(256) void prep_count(
    const float* __restrict__ W, short* __restrict__ Wt, int* __restrict__ off,
    const int* __restrict__ ei, int* __restrict__ hist2d,
    int E, int N, int NBUCK, int NB, int Etot)
{
    const int blk = blockIdx.x, t = threadIdx.x;
    if (blk < 256) {
        int id = blk * 256 + t;
        int n = id >> 8, k = id & 255;
        Wt[id] = f2bf(W[k * 256 + n]);
        if (id == 0) off[N] = Etot;
        return;
    }
    extern __shared__ int lh[];           // NBUCK ints
    const int cblk = blk - 256;
    for (int b = t; b < NBUCK; b += 256) lh[b] = 0;
    __syncthreads();
    const int e0 = cblk * EPB;
    if (e0 + EPB <= E) {                  // fast path: int4 dst loads
#pragma unroll
        for (int i = 0; i < EPB / 1024; ++i) {
            int e = e0 + i * 1024 + t * 4;
            int4 d = *(const int4*)(ei + E + e);
            atomicAdd(&lh[d.x >> BSH], 1);
            atomicAdd(&lh[d.y >> BSH], 1);
            atomicAdd(&lh[d.z >> BSH], 1);
            atomicAdd(&lh[d.w >> BSH], 1);
        }
    } else {                              // boundary / self-loop blocks
        for (int i = 0; i < EPB / 256; ++i) {
            int e = e0 + i * 256 + t;
            if (e < Etot) {
                int dte = (e < E) ? ei[E + e] : (e - E);
                atomicAdd(&lh[dte >> BSH], 1);
            }
        }
    }
    __syncthreads();
    for (int b = t; b < NBUCK; b += 256) hist2d[b * NB + cblk] = lh[b];
}

// ---------------------------------------------------------------------------
// Kernel 1: MFMA GEMM, double-buffered LDS (ONE sync per k-step).
// 512 threads = 8 waves (2 node-halves x 4 heads). Block: 256 ch x 128 nodes.
// h^T layout D[ch][node]; lane holds 4 contiguous channels of one node.
// ---------------------------------------------------------------------------
__global__ __launch_bounds__(512) void gemm_attn(
    const float* __restrict__ x, const short* __restrict__ Wt,
    const float* __restrict__ att_src, const float* __restrict__ att_dst,
    short* __restrict__ hb, float* __restrict__ a_src_n,
    float* __restrict__ a_dst_n, int M)
{
    __shared__ __align__(16) short xs[2][128][32];   // double buffer, 16 KB
    const int t = threadIdx.x;
    const int lane = t & 63, wv = t >> 6;
    const int wr = wv >> 2;                       // node half
    const int hd = wv & 3;                        // head (64 channels)
    const int quad = lane >> 4, l15 = lane & 15;
    const int n0 = blockIdx.x * 128;

    const int row = t >> 2, kq = t & 3;           // 512 threads cover 128x32
    const bool okr = (n0 + row) < M;
    const float* xp = x + (size_t)(n0 + row) * 256 + kq * 8;

    const short* wbase = Wt + (size_t)(hd * 64 + l15) * 256 + quad * 8;

    f4 acc[4][4];   // [i: ch frag][j: node frag]
#pragma unroll
    for (int i = 0; i < 4; ++i)
#pragma unroll
        for (int j = 0; j < 4; ++j) acc[i][j] = (f4)(0.f);

    float4 v0 = {}, v1 = {};
    if (okr) { const float4* p = (const float4*)xp; v0 = p[0]; v1 = p[1]; }

    int buf = 0;
#pragma unroll
    for (int ks = 0; ks < 8; ++ks) {
        uint4 u = { pk2(v0.x, v0.y), pk2(v0.z, v0.w), pk2(v1.x, v1.y), pk2(v1.z, v1.w) };
        *(uint4*)&xs[buf][row][kq * 8] = u;
        __syncthreads();

        if (ks < 7 && okr) {              // prefetch next k-step (overlaps MFMA)
            const float4* p = (const float4*)(xp + (ks + 1) * 32);
            v0 = p[0]; v1 = p[1];
        }

        s8 af[4], bf[4];
#pragma unroll
        for (int i = 0; i < 4; ++i)
            af[i] = *(const s8*)(wbase + (size_t)(i * 16) * 256 + ks * 32);
#pragma unroll
        for (int j = 0; j < 4; ++j)
            bf[j] = *(const s8*)&xs[buf][wr * 64 + j * 16 + l15][quad * 8];
#pragma unroll
        for (int i = 0; i < 4; ++i)
#pragma unroll
            for (int j = 0; j < 4; ++j)
                acc[i][j] = __builtin_amdgcn_mfma_f32_16x16x32_bf16(af[i], bf[j], acc[i][j], 0, 0, 0);
        buf ^= 1;
    }

    float asv[4][4], adv[4][4];
#pragma unroll
    for (int i = 0; i < 4; ++i)
#pragma unroll
        for (int rr = 0; rr < 4; ++rr) {
            asv[i][rr] = att_src[hd * 64 + i * 16 + quad * 4 + rr];
            adv[i][rr] = att_dst[hd * 64 + i * 16 + quad * 4 + rr];
        }

#pragma unroll
    for (int j = 0; j < 4; ++j) {
        const int node = n0 + wr * 64 + j * 16 + l15;
        const bool ok = node < M;
        float ps = 0.f, pd = 0.f;
#pragma unroll
        for (int i = 0; i < 4; ++i)
#pragma unroll
            for (int rr = 0; rr < 4; ++rr) {
                float v = acc[i][j][rr];
                ps = fmaf(v, asv[i][rr], ps);
                pd = fmaf(v, adv[i][rr], pd);
            }
        ps += __shfl_xor(ps, 16); ps += __shfl_xor(ps, 32);
        pd += __shfl_xor(pd, 16); pd += __shfl_xor(pd, 32);
        if (ok && quad == 0) {
            a_src_n[node * 4 + hd] = ps;
            a_dst_n[node * 4 + hd] = pd;
        }
        if (ok) {
#pragma unroll
            for (int i = 0; i < 4; ++i) {
                uint2 pk = make_uint2(pk2(acc[i][j][0], acc[i][j][1]),
                                      pk2(acc[i][j][2], acc[i][j][3]));
                *(uint2*)&hb[(size_t)node * 256 + hd * 64 + i * 16 + quad * 4] = pk;
            }
        }
    }
}

// ---------------------------------------------------------------------------
// Kernels 2a/2b: two-level exclusive scan of hist2d (Ntot elems).
// Final value of element idx = scanned[idx] + bexc[idx>>10].
// ---------------------------------------------------------------------------
__global__ __launch_bounds__(1024) void scan1(const int* __restrict__ src,
                                              int* __restrict__ dst,
                                              int* __restrict__ bsum, int Ntot)
{
    __shared__ int wsum[16], wexc[16];
    const int t = threadIdx.x, lane = t & 63, w = t >> 6;
    const int idx = blockIdx.x * 1024 + t;
    int v = (idx < Ntot) ? src[idx] : 0;
    int val = v;
#pragma unroll
    for (int o = 1; o < 64; o <<= 1) {
        int u = __shfl_up(val, o);
        if (lane >= o) val += u;
    }
    if (lane == 63) wsum[w] = val;
    __syncthreads();
    if (t < 16) {
        int s = wsum[t];
#pragma unroll
        for (int o = 1; o < 16; o <<= 1) {
            int u = __shfl_up(s, o, 16);
            if (t >= o) s += u;
        }
        wexc[t] = s - wsum[t];
        if (t == 15) bsum[blockIdx.x] = s;
    }
    __syncthreads();
    if (idx < Ntot) dst[idx] = wexc[w] + val - v;
}

__global__ __launch_bounds__(1024) void scan2v(const int* __restrict__ bsum,
                                               int* __restrict__ bexc, int nb)
{
    __shared__ int wsum[16], wexc[16];
    const int t = threadIdx.x, lane = t & 63, w = t >> 6;
    int v = (t < nb) ? bsum[t] : 0;
    int val = v;
#pragma unroll
    for (int o = 1; o < 64; o <<= 1) {
        int u = __shfl_up(val, o);
        if (lane >= o) val += u;
    }
    if (lane == 63) wsum[w] = val;
    __syncthreads();
    if (t < 16) {
        int s = wsum[t];
#pragma unroll
        for (int o = 1; o < 16; o <<= 1) {
            int u = __shfl_up(s, o, 16);
            if (t >= o) s += u;
        }
        wexc[t] = s - wsum[t];
    }
    __syncthreads();
    if (t < nb) bexc[t] = wexc[w] + val - v;
}

// ---------------------------------------------------------------------------
// Kernel 3: bucket scatter (bexc applied inline); int4 edge loads fast path.
// Entry packed: src | (dst&31)<<20
// ---------------------------------------------------------------------------
__global__ __launch_bounds__(256) void scatter2(const int* __restrict__ ei,
                                                const int* __restrict__ scanned,
                                                const int* __restrict__ bexc,
                                                unsigned* __restrict__ bucketed,
                                                int E, int N, int NBUCK, int NB)
{
    extern __shared__ int lcur[];          // NBUCK ints
    const int t = threadIdx.x, blk = blockIdx.x;
    for (int b = t; b < NBUCK; b += 256) {
        int idx = b * NB + blk;
        lcur[b] = scanned[idx] + bexc[idx >> 10];
    }
    __syncthreads();
    const int e0 = blk * EPB, Etot = E + N;
    if (e0 + EPB <= E) {                  // fast path: int4 src+dst loads
#pragma unroll
        for (int i = 0; i < EPB / 1024; ++i) {
            int e = e0 + i * 1024 + t * 4;
            int4 s4 = *(const int4*)(ei + e);
            int4 d4 = *(const int4*)(ei + E + e);
            int p0 = atomicAdd(&lcur[d4.x >> BSH], 1);
            bucketed[p0] = (unsigned)s4.x | ((unsigned)(d4.x & 31) << 20);
            int p1 = atomicAdd(&lcur[d4.y >> BSH], 1);
            bucketed[p1] = (unsigned)s4.y | ((unsigned)(d4.y & 31) << 20);
            int p2 = atomicAdd(&lcur[d4.z >> BSH], 1);
            bucketed[p2] = (unsigned)s4.z | ((unsigned)(d4.z & 31) << 20);
            int p3 = atomicAdd(&lcur[d4.w >> BSH], 1);
            bucketed[p3] = (unsigned)s4.w | ((unsigned)(d4.w & 31) << 20);
        }
    } else {
        for (int i = 0; i < EPB / 256; ++i) {
            int e = e0 + i * 256 + t;
            if (e < Etot) {
                int src, dte;
                if (e < E) { src = ei[e]; dte = ei[E + e]; }
                else       { src = e - E; dte = src; }
                int pos = atomicAdd(&lcur[dte >> BSH], 1);
                bucketed[pos] = (unsigned)src | ((unsigned)(dte & 31) << 20);
            }
        }
    }
}

// ---------------------------------------------------------------------------
// Kernel 4: csr_build — one block per bucket: group entries by dst into
// global csr (dst-sorted) + off[n]. Per-WAVE cursor rows cut LDS-atomic
// same-address serialization 4x.
// ---------------------------------------------------------------------------
__global__ __launch_bounds__(256) void csr_build(
    const unsigned* __restrict__ bucketed, const int* __restrict__ scanned,
    const int* __restrict__ bexc, int* __restrict__ off, int* __restrict__ csr,
    int N, int NB, int NBUCK, int Etot)
{
    __shared__ unsigned est[2048];
    __shared__ int ldeg4[4][32], lcur4[4][32], loff[32];
    const int t = threadIdx.x, wv = t >> 6, b = blockIdx.x;

    const int i0 = b * NB;
    const int gbase = scanned[i0] + bexc[i0 >> 10];
    int gend;
    if (b + 1 == NBUCK) gend = Etot;
    else { int i1 = (b + 1) * NB; gend = scanned[i1] + bexc[i1 >> 10]; }
    int cnt = gend - gbase;
    if (cnt > 2048) cnt = 2048;            // never hit (~545 avg)

    if (t < 128) ldeg4[t >> 5][t & 31] = 0;
    __syncthreads();
    for (int i = t; i < cnt; i += 256) {
        unsigned en = bucketed[gbase + i];
        est[i] = en;
        atomicAdd(&ldeg4[wv][en >> 20], 1);
    }
    __syncthreads();
    if (t < 32) {
        int d0 = ldeg4[0][t], d1 = ldeg4[1][t], d2 = ldeg4[2][t], d3 = ldeg4[3][t];
        int tot = d0 + d1 + d2 + d3;
        int val = tot;
#pragma unroll
        for (int o = 1; o < 32; o <<= 1) {
            int u = __shfl_up(val, o, 32);
            if (t >= o) val += u;
        }
        int excl = val - tot;
        loff[t] = excl;
        lcur4[0][t] = excl;
        lcur4[1][t] = excl + d0;
        lcur4[2][t] = excl + d0 + d1;
        lcur4[3][t] = excl + d0 + d1 + d2;
    }
    __syncthreads();
    for (int i = t; i < cnt; i += 256) {
        unsigned en = est[i];
        int pos = atomicAdd(&lcur4[wv][en >> 20], 1);
        csr[gbase + pos] = (int)(en & 0xFFFFF);
    }
    if (t < 32) {
        int n = (b << BSH) + t;
        if (n < N) off[n] = gbase + loff[t];
    }
}

// ---------------------------------------------------------------------------
// Kernel 5: aggregate (unchanged from R7 — proven 68 µs, zero conflicts).
// ---------------------------------------------------------------------------
__global__ __launch_bounds__(256) void aggregate(const short* __restrict__ hb,
                                                 const float* __restrict__ a_src_n,
                                                 const float* __restrict__ a_dst_n,
                                                 const int* __restrict__ off,
                                                 const int* __restrict__ csr,
                                                 const float* __restrict__ bias,
                                                 float* __restrict__ out, int N)
{
    __shared__ float lds_w[4][64][4];
    __shared__ int   lds_s[4][64];
    const int wv = threadIdx.x >> 6;
    const int lane = threadIdx.x & 63;
    const int half = lane >> 5, l31 = lane & 31;
    const int n = blockIdx.x * 4 + wv;
    if (n >= N) return;

    const int base = off[n];
    const int d = off[n + 1] - base;
    const float4 ad = *(const float4*)(a_dst_n + 4 * n);
    const int hl = l31 >> 3;             // head of this lane's 8 channels

    float acc[8] = {0.f, 0.f, 0.f, 0.f, 0.f, 0.f, 0.f, 0.f};
    float4 sum = make_float4(0.f, 0.f, 0.f, 0.f);
    const uint4* hp = (const uint4*)hb;

    for (int c0 = 0; c0 < d; c0 += 64) {
        int j = c0 + lane;
        int s = 0;
        float4 w4 = make_float4(0.f, 0.f, 0.f, 0.f);
        if (j < d) {
            s = csr[base + j];
            float4 as = *(const float4*)(a_src_n + 4 * s);
            float lx = as.x + ad.x; lx = lx >= 0.f ? lx : NEG * lx;
            float ly = as.y + ad.y; ly = ly >= 0.f ? ly : NEG * ly;
            float lz = as.z + ad.z; lz = lz >= 0.f ? lz : NEG * lz;
            float lw = as.w + ad.w; lw = lw >= 0.f ? lw : NEG * lw;
            w4 = make_float4(__expf(lx), __expf(ly), __expf(lz), __expf(lw));
        }
        sum.x += w4.x; sum.y += w4.y; sum.z += w4.z; sum.w += w4.w;
        *(float4*)&lds_w[wv][lane][0] = w4;
        lds_s[wv][lane] = s;
        __builtin_amdgcn_wave_barrier();

        const int cl = (d - c0) < 64 ? (d - c0) : 64;
        int jj = 0;
        for (; jj + 4 <= cl; jj += 4) {
            int   s0 = lds_s[wv][jj + half];
            int   s1 = lds_s[wv][jj + 2 + half];
            float w0 = lds_w[wv][jj + half][hl];
            float w1 = lds_w[wv][jj + 2 + half][hl];
            uint4 v0 = hp[(size_t)s0 * 32 + l31];
            uint4 v1 = hp[(size_t)s1 * 32 + l31];
            acc[0] = fmaf(w0, bf2f((unsigned short)(v0.x & 0xffff)), acc[0]);
            acc[1] = fmaf(w0, bf2f((unsigned short)(v0.x >> 16)),    acc[1]);
            acc[2] = fmaf(w0, bf2f((unsigned short)(v0.y & 0xffff)), acc[2]);
            acc[3] = fmaf(w0, bf2f((unsigned short)(v0.y >> 16)),    acc[3]);
            acc[4] = fmaf(w0, bf2f((unsigned short)(v0.z & 0xffff)), acc[4]);
            acc[5] = fmaf(w0, bf2f((unsigned short)(v0.z >> 16)),    acc[5]);
            acc[6] = fmaf(w0, bf2f((unsigned short)(v0.w & 0xffff)), acc[6]);
            acc[7] = fmaf(w0, bf2f((unsigned short)(v0.w >> 16)),    acc[7]);
            acc[0] = fmaf(w1, bf2f((unsigned short)(v1.x & 0xffff)), acc[0]);
            acc[1] = fmaf(w1, bf2f((unsigned short)(v1.x >> 16)),    acc[1]);
            acc[2] = fmaf(w1, bf2f((unsigned short)(v1.y & 0xffff)), acc[2]);
            acc[3] = fmaf(w1, bf2f((unsigned short)(v1.y >> 16)),    acc[3]);
            acc[4] = fmaf(w1, bf2f((unsigned short)(v1.z & 0xffff)), acc[4]);
            acc[5] = fmaf(w1, bf2f((unsigned short)(v1.z >> 16)),    acc[5]);
            acc[6] = fmaf(w1, bf2f((unsigned short)(v1.w & 0xffff)), acc[6]);
            acc[7] = fmaf(w1, bf2f((unsigned short)(v1.w >> 16)),    acc[7]);
        }
        for (; jj < cl; jj += 2) {   // tail: lds_s/lds_w initialized for all 64
            int   s0 = lds_s[wv][jj + half];
            float w0 = lds_w[wv][jj + half][hl];
            uint4 v0 = hp[(size_t)s0 * 32 + l31];
            acc[0] = fmaf(w0, bf2f((unsigned short)(v0.x & 0xffff)), acc[0]);
            acc[1] = fmaf(w0, bf2f((unsigned short)(v0.x >> 16)),    acc[1]);
            acc[2] = fmaf(w0, bf2f((unsigned short)(v0.y & 0xffff)), acc[2]);
            acc[3] = fmaf(w0, bf2f((unsigned short)(v0.y >> 16)),    acc[3]);
            acc[4] = fmaf(w0, bf2f((unsigned short)(v0.z & 0xffff)), acc[4]);
            acc[5] = fmaf(w0, bf2f((unsigned short)(v0.z >> 16)),    acc[5]);
            acc[6] = fmaf(w0, bf2f((unsigned short)(v0.w & 0xffff)), acc[6]);
            acc[7] = fmaf(w0, bf2f((unsigned short)(v0.w >> 16)),    acc[7]);
        }
        __builtin_amdgcn_wave_barrier();
    }

#pragma unroll
    for (int k = 0; k < 8; ++k) acc[k] += __shfl_xor(acc[k], 32);

#pragma unroll
    for (int o = 32; o > 0; o >>= 1) {
        sum.x += __shfl_xor(sum.x, o);
        sum.y += __shfl_xor(sum.y, o);
        sum.z += __shfl_xor(sum.z, o);
        sum.w += __shfl_xor(sum.w, o);
    }
    float sh = (hl & 2) ? ((hl & 1) ? sum.w : sum.z) : ((hl & 1) ? sum.y : sum.x);
    float ih = 1.f / (sh + 1e-16f);

    if (half == 0) {
        const float4* bp = (const float4*)bias + l31 * 2;
        float4 b0 = bp[0], b1 = bp[1];
        float4 o0, o1;
        o0.x = fmaxf(fmaf(acc[0], ih, b0.x), 0.f);
        o0.y = fmaxf(fmaf(acc[1], ih, b0.y), 0.f);
        o0.z = fmaxf(fmaf(acc[2], ih, b0.z), 0.f);
        o0.w = fmaxf(fmaf(acc[3], ih, b0.w), 0.f);
        o1.x = fmaxf(fmaf(acc[4], ih, b1.x), 0.f);
        o1.y = fmaxf(fmaf(acc[5], ih, b1.y), 0.f);
        o1.z = fmaxf(fmaf(acc[6], ih, b1.z), 0.f);
        o1.w = fmaxf(fmaf(acc[7], ih, b1.w), 0.f);
        float4* op = (float4*)(out + (size_t)n * 256) + l31 * 2;
        op[0] = o0;
        op[1] = o1;
    }
}

// ---------------------------------------------------------------------------
extern "C" void kernel_launch(void* const* d_in, const int* in_sizes, int n_in,
                              void* d_out, int out_size, void* d_ws, size_t ws_size,
                              hipStream_t stream)
{
    const float* x       = (const float*)d_in[0];
    const int*   ei      = (const int*)d_in[1];
    const float* W       = (const float*)d_in[2];
    const float* att_src = (const float*)d_in[3];
    const float* att_dst = (const float*)d_in[4];
    const float* bias    = (const float*)d_in[5];
    float* out = (float*)d_out;

    const int N = in_sizes[0] / 256;       // 50000
    const int E = in_sizes[1] / 2;         // 800000
    const int Etot = E + N;                // 850000
    const int NBUCK = (N + 31) >> BSH;     // 1563
    const int NB = (Etot + EPB - 1) / EPB; // 416
    const int Ntot = NBUCK * NB;           // ~650k
    const int nb1 = (Ntot + 1023) / 1024;  // ~636

    // workspace carve (~45 MB; ws >= 56 MB)
    char* p = (char*)d_ws;
    short*    hb      = (short*)p;    p += (size_t)N * 256 * sizeof(short);
    short*    Wt      = (short*)p;    p += 256 * 256 * sizeof(short);
    float*    a_src_n = (float*)p;    p += (size_t)N * 4 * sizeof(float);
    float*    a_dst_n = (float*)p;    p += (size_t)N * 4 * sizeof(float);
    int*      hist2d  = (int*)p;      p += (size_t)Ntot * sizeof(int);
    int*      scanned = (int*)p;      p += (size_t)Ntot * sizeof(int);
    int*      bsum    = (int*)p;      p += 1024 * sizeof(int);
    int*      bexc    = (int*)p;      p += 1024 * sizeof(int);
    int*      off     = (int*)p;      p += (size_t)(N + 1) * sizeof(int);
    unsigned* bucketed= (unsigned*)p; p += (size_t)Etot * sizeof(unsigned);
    int*      csr     = (int*)p;      p += (size_t)Etot * sizeof(int);

    prep_count<<<256 + NB, 256, NBUCK * sizeof(int), stream>>>(
        W, Wt, off, ei, hist2d, E, N, NBUCK, NB, Etot);
    gemm_attn<<<(N + 127) / 128, 512, 0, stream>>>(
        x, Wt, att_src, att_dst, hb, a_src_n, a_dst_n, N);
    scan1<<<nb1, 1024, 0, stream>>>(hist2d, scanned, bsum, Ntot);
    scan2v<<<1, 1024, 0, stream>>>(bsum, bexc, nb1);
    scatter2<<<NB, 256, NBUCK * sizeof(int), stream>>>(ei, scanned, bexc, bucketed,
                                                       E, N, NBUCK, NB);
    csr_build<<<NBUCK, 256, 0, stream>>>(bucketed, scanned, bexc, off, csr,
                                         N, NB, NBUCK, Etot);
    aggregate<<<(N + 3) / 4, 256, 0, stream>>>(hb, a_src_n, a_dst_n, off, csr,
                                               bias, out, N);
}